// Round 1
// 210.274 us; speedup vs baseline: 1.1699x; 1.1699x over previous
//
#include <hip/hip_runtime.h>
#include <hip/hip_bf16.h>

#define N_NODES 50000
#define N_EDGES 800000
#define D 128
#define L_LAYERS 3
#define BN_EPS 1e-5f
#define NBUK 196          // buckets of 256 dst values: 196*256 = 50176 >= 50000
#define BIN_CHUNK 4096    // edges per block in bin: 196*4096 >= 800000
#define NBIN_BLOCKS 196
#define BSTRIDE 5120      // fixed per-bucket bin region (words); max bucket ~4350
#define CSTRIDE 5376      // fixed per-bucket csr region (padded; max ~4350+768)
#define AROW 68           // LDS row stride in words (16B aligned, low conflicts)
#define NPART 8           // BN stat partial buffers (atomic contention spread)
#define PADOFF (N_NODES << 8)   // byte offset of the zero pad row

typedef __attribute__((ext_vector_type(8))) short short8;
typedef __attribute__((ext_vector_type(4))) float floatx4;
typedef __attribute__((ext_vector_type(4))) unsigned short ushort4v;

__device__ __forceinline__ unsigned short f2bf(float f) {
    unsigned u = __builtin_bit_cast(unsigned, f);
    u += 0x7FFFu + ((u >> 16) & 1u);   // round-to-nearest-even
    return (unsigned short)(u >> 16);
}
__device__ __forceinline__ float bf2f(unsigned short h) {
    unsigned u = ((unsigned)h) << 16;
    return __builtin_bit_cast(float, u);
}
__device__ __forceinline__ float bf2f_lo(unsigned p) {
    return __builtin_bit_cast(float, p << 16);
}
__device__ __forceinline__ float bf2f_hi(unsigned p) {
    return __builtin_bit_cast(float, p & 0xFFFF0000u);
}

__device__ __forceinline__ int edge_at(const void* ei, const int* flag64, long long i) {
    if (*flag64) return (int)((const long long*)ei)[i];
    return ((const int*)ei)[i];
}

// ---------------------------------------------------------------------------
// Merged one-time prep: block 0 detects i64-vs-i32 edge layout, zeroes the
// counter/stats region and the pad row of xb; blocks 1..48 permute weights
// into MFMA B-fragment bf16 layout; remaining blocks convert x -> bf16.
__global__ __launch_bounds__(256) void prep_kernel(const float* __restrict__ x,
        const void* __restrict__ ei, int* __restrict__ flag,
        const float* __restrict__ W1, const float* __restrict__ W2,
        short* __restrict__ Wp, unsigned short* __restrict__ xb,
        unsigned* __restrict__ zreg, int zwords) {
    int bid = blockIdx.x;
    int t = threadIdx.x;
    if (bid == 0) {
        __shared__ int nz;
        if (t == 0) nz = 0;
        __syncthreads();
        if (((const int*)ei)[2 * t + 1] != 0) atomicAdd(&nz, 1);
        __syncthreads();
        if (t == 0) *flag = (nz == 0) ? 1 : 0;
        for (int i = t; i < zwords; i += 256) zreg[i] = 0u;
        if (t < 64) ((unsigned*)(xb + (size_t)N_NODES * D))[t] = 0u;  // zero pad row
    } else if (bid <= 48) {
        int tid = (bid - 1) * 256 + t;   // 6*2048 total
        int mat = tid >> 11;
        int t2 = tid & 2047;
        int kt = t2 >> 9;
        int nt = (t2 >> 6) & 7;
        int lane = t2 & 63;
        const float* W = (mat < 3) ? (W1 + (size_t)mat * D * D)
                                   : (W2 + (size_t)(mat - 3) * D * D);
        int kbase = kt * 32 + (lane >> 4) * 8;
        int n = nt * 16 + (lane & 15);
        short8 frag;
        #pragma unroll
        for (int j = 0; j < 8; j++) frag[j] = (short)f2bf(W[(kbase + j) * D + n]);
        *(short8*)(Wp + (size_t)mat * D * D + (size_t)t2 * 8) = frag;
    } else {
        long long i = (long long)((bid - 49) * 256 + t) * 4;
        float4 v = *(const float4*)(x + i);
        ushort4v o;
        o.x = f2bf(v.x); o.y = f2bf(v.y); o.z = f2bf(v.z); o.w = f2bf(v.w);
        *(ushort4v*)(xb + i) = o;
    }
}

// ---------------------------------------------------------------------------
// CSR stage 1 (merged count+bin): single pass. Each block histograms its
// 4096 edges in LDS, reserves per-bucket ranges in FIXED-stride regions via
// global cursors (cursor final value == bucket count), writes packed words.
// word = (src << 8) | (dst & 255).
__global__ __launch_bounds__(256) void bin_kernel(const void* __restrict__ ei,
        const int* __restrict__ flag64, int* __restrict__ bucketCursor,
        unsigned* __restrict__ binned) {
    __shared__ int lhist[NBUK];
    __shared__ int gbase[NBUK];
    int t = threadIdx.x;
    for (int i = t; i < NBUK; i += 256) lhist[i] = 0;
    __syncthreads();

    int e0 = blockIdx.x * BIN_CHUNK;
    unsigned w[BIN_CHUNK / 256];
    short bkt[BIN_CHUNK / 256];
    short lidx[BIN_CHUNK / 256];
    #pragma unroll
    for (int i = 0; i < BIN_CHUNK / 256; i++) {
        int e = e0 + t + i * 256;
        if (e < N_EDGES) {
            int s = edge_at(ei, flag64, e);
            int d = edge_at(ei, flag64, (long long)N_EDGES + e);
            int b = d >> 8;
            w[i] = ((unsigned)s << 8) | (unsigned)(d & 255);
            bkt[i] = (short)b;
            lidx[i] = (short)atomicAdd(&lhist[b], 1);
        } else {
            bkt[i] = -1;
        }
    }
    __syncthreads();
    for (int i = t; i < NBUK; i += 256) {
        int c = lhist[i];
        gbase[i] = i * BSTRIDE + (c ? atomicAdd(&bucketCursor[i], c) : 0);
    }
    __syncthreads();
    #pragma unroll
    for (int i = 0; i < BIN_CHUNK / 256; i++) {
        if (bkt[i] >= 0)
            binned[gbase[bkt[i]] + (int)lidx[i]] = w[i];
    }
}

// CSR stage 2: one block per bucket; fixed CSTRIDE region per bucket.
// Each row's entry list is padded to a multiple of 4 with the zero-row
// offset, and entries are stored as PRE-SHIFTED byte offsets (src<<8) so the
// gather needs only 32-bit adds. bucketEnd[b] records the padded end of the
// bucket (used as `end` for the last row of each bucket).
__global__ __launch_bounds__(256) void csr_build_kernel(const unsigned* __restrict__ binned,
        const int* __restrict__ bucketCursor, int* __restrict__ rowptr,
        int* __restrict__ bucketEnd, int* __restrict__ csr) {
    __shared__ int ls[256];
    __shared__ int lhist[256];
    __shared__ int lcur[256];
    int b = blockIdx.x, t = threadIdx.x;
    int n = bucketCursor[b];
    const unsigned* src = binned + (size_t)b * BSTRIDE;

    lhist[t] = 0;
    __syncthreads();
    for (int i = t; i < n; i += 256)
        atomicAdd(&lhist[src[i] & 255u], 1);
    __syncthreads();
    int c = lhist[t];
    int pc = (c + 3) & ~3;           // pad each row to a multiple of 4
    ls[t] = pc;
    __syncthreads();
    for (int off = 1; off < 256; off <<= 1) {
        int u = (t >= off) ? ls[t - off] : 0;
        __syncthreads();
        ls[t] += u;
        __syncthreads();
    }
    int excl = ls[t] - pc;
    int base = b * CSTRIDE;
    int dst = b * 256 + t;
    if (dst <= N_NODES) rowptr[dst] = base + excl;
    if (t == 0) bucketEnd[b] = base + ls[255];
    lcur[t] = excl;
    __syncthreads();
    for (int i = t; i < n; i += 256) {
        unsigned wv = src[i];
        int pos = atomicAdd(&lcur[wv & 255u], 1);
        csr[base + pos] = (int)(wv & 0xFFFFFF00u);   // src byte-offset (src<<8)
    }
    __syncthreads();
    // fill this row's pad slots with the zero-row offset
    for (int i = lcur[t]; i < excl + pc; i++)
        csr[base + i] = PADOFF;
}

// ---------------------------------------------------------------------------
// Fused gather + GEMM1. 256-thread block = 4 waves over a 16-row tile
// (dynamic row queue). Gather: wave splits into 4x16-lane groups; each lane
// loads 16 B (8 cols) so one dwordx4 + one bpermute covers 4 edges (CSR is
// padded to x4, entries are pre-shifted byte offsets -> pure 32-bit adds).
// Then group-reduce (xor16/32), L2 norms, pack to bf16 in LDS; 4-wave MFMA
// (2 nt columns-of-16 per wave); BN stats into NPART partial buffers.
__global__ __launch_bounds__(256, 8) void gather_gemm1_kernel(
        const unsigned short* __restrict__ xb,
        const int* __restrict__ rowptr, const int* __restrict__ csr,
        const int* __restrict__ bucketEnd,
        const float* __restrict__ epsArr, int layer,
        const short* __restrict__ Wp, const float* __restrict__ bB,
        unsigned* __restrict__ Hout,      // bf16 pairs, 64 words per row
        float* __restrict__ gsum, float* __restrict__ gsq) {
    __shared__ __attribute__((aligned(16))) unsigned lA[16 * AROW];  // 4352 B
    __shared__ int wq;
    const char* xbase = (const char*)xb;
    int wave = threadIdx.x >> 6, lane = threadIdx.x & 63;
    int g = lane >> 4, p = lane & 15;
    unsigned po = (unsigned)(p << 4);
    int r0 = blockIdx.x * 16;
    float eps1 = 1.0f + epsArr[layer];
    if (threadIdx.x == 0) wq = 0;
    __syncthreads();

    // ---- gather phase: dynamic row queue; 4 edges per wave iteration ----
    for (;;) {
        int r;
        if (lane == 0) r = atomicAdd(&wq, 1);
        r = __shfl(r, 0);
        if (r >= 16) break;
        int row = r0 + r;
        int beg = rowptr[row];
        int end = ((row & 255) == 255) ? bucketEnd[row >> 8] : rowptr[row + 1];
        float ac[8];
        #pragma unroll
        for (int k = 0; k < 8; k++) ac[k] = 0.f;
        for (int base = beg; base < end; base += 64) {
            int n = end - base;
            if (n > 64) n = 64;
            unsigned idxv = (lane < n) ? (unsigned)csr[base + lane] : (unsigned)PADOFF;
            int j = 0;
            for (; j + 8 <= n; j += 8) {     // 8 edges: 2 loads in flight
                unsigned o0 = (unsigned)__shfl((int)idxv, j + g) + po;
                unsigned o1 = (unsigned)__shfl((int)idxv, j + 4 + g) + po;
                uint4 v0 = *(const uint4*)(xbase + o0);
                uint4 v1 = *(const uint4*)(xbase + o1);
                ac[0] += bf2f_lo(v0.x); ac[1] += bf2f_hi(v0.x);
                ac[2] += bf2f_lo(v0.y); ac[3] += bf2f_hi(v0.y);
                ac[4] += bf2f_lo(v0.z); ac[5] += bf2f_hi(v0.z);
                ac[6] += bf2f_lo(v0.w); ac[7] += bf2f_hi(v0.w);
                ac[0] += bf2f_lo(v1.x); ac[1] += bf2f_hi(v1.x);
                ac[2] += bf2f_lo(v1.y); ac[3] += bf2f_hi(v1.y);
                ac[4] += bf2f_lo(v1.z); ac[5] += bf2f_hi(v1.z);
                ac[6] += bf2f_lo(v1.w); ac[7] += bf2f_hi(v1.w);
            }
            if (j < n) {                      // residual 4 edges
                unsigned o0 = (unsigned)__shfl((int)idxv, j + g) + po;
                uint4 v0 = *(const uint4*)(xbase + o0);
                ac[0] += bf2f_lo(v0.x); ac[1] += bf2f_hi(v0.x);
                ac[2] += bf2f_lo(v0.y); ac[3] += bf2f_hi(v0.y);
                ac[4] += bf2f_lo(v0.z); ac[5] += bf2f_hi(v0.z);
                ac[6] += bf2f_lo(v0.w); ac[7] += bf2f_hi(v0.w);
            }
        }
        // combine the 4 group partials: every lane ends with group-summed cols
        #pragma unroll
        for (int k = 0; k < 8; k++) {
            ac[k] += __shfl_xor(ac[k], 16);
            ac[k] += __shfl_xor(ac[k], 32);
        }
        // self row + L2 norms
        uint4 sv = *(const uint4*)(xbase + (((unsigned)row << 8) + po));
        float xv[8];
        xv[0] = bf2f_lo(sv.x); xv[1] = bf2f_hi(sv.x);
        xv[2] = bf2f_lo(sv.y); xv[3] = bf2f_hi(sv.y);
        xv[4] = bf2f_lo(sv.z); xv[5] = bf2f_hi(sv.z);
        xv[6] = bf2f_lo(sv.w); xv[7] = bf2f_hi(sv.w);
        float sa = 0.f, sx = 0.f;
        #pragma unroll
        for (int k = 0; k < 8; k++) { sa += ac[k] * ac[k]; sx += xv[k] * xv[k]; }
        #pragma unroll
        for (int mm = 8; mm >= 1; mm >>= 1) {
            sa += __shfl_xor(sa, mm);
            sx += __shfl_xor(sx, mm);
        }
        float ra = 1.0f / fmaxf(sqrtf(sa), 1e-12f);
        float rx = eps1 / fmaxf(sqrtf(sx), 1e-12f);
        unsigned wds[4];
        #pragma unroll
        for (int k = 0; k < 4; k++) {
            float lo = ac[2 * k] * ra + xv[2 * k] * rx;
            float hi = ac[2 * k + 1] * ra + xv[2 * k + 1] * rx;
            wds[k] = (unsigned)f2bf(lo) | ((unsigned)f2bf(hi) << 16);
        }
        if (g == 0)
            *(uint4*)(lA + r * AROW + p * 4) = make_uint4(wds[0], wds[1], wds[2], wds[3]);
    }
    __syncthreads();

    // ---- MFMA phase: wave w covers cols [32w, 32w+32) via nt0/nt1 ----
    int m = p;
    int nt0 = wave * 2, nt1 = nt0 + 1;
    short8 afr[4];
    #pragma unroll
    for (int kt = 0; kt < 4; kt++)
        afr[kt] = *(const short8*)(lA + m * AROW + kt * 16 + g * 4);
    __syncthreads();   // all A-frag reads done; lA becomes the H staging tile

    floatx4 acc0 = (floatx4){0.f, 0.f, 0.f, 0.f};
    floatx4 acc1 = (floatx4){0.f, 0.f, 0.f, 0.f};
    #pragma unroll
    for (int kt = 0; kt < 4; kt++) {
        short8 bf0 = *(const short8*)(Wp + (size_t)((kt * 8 + nt0) * 64 + lane) * 8);
        short8 bf1 = *(const short8*)(Wp + (size_t)((kt * 8 + nt1) * 64 + lane) * 8);
        acc0 = __builtin_amdgcn_mfma_f32_16x16x32_bf16(afr[kt], bf0, acc0, 0, 0, 0);
        acc1 = __builtin_amdgcn_mfma_f32_16x16x32_bf16(afr[kt], bf1, acc1, 0, 0, 0);
    }

    unsigned short* hlds = (unsigned short*)lA;
    float bc0 = bB[nt0 * 16 + m], bc1 = bB[nt1 * 16 + m];
    float s0 = 0.f, q0 = 0.f, s1 = 0.f, q1 = 0.f;
    #pragma unroll
    for (int r = 0; r < 4; r++) {
        int lrow = g * 4 + r;
        float h0 = acc0[r] + bc0;
        float h1 = acc1[r] + bc1;
        hlds[lrow * (AROW * 2) + nt0 * 16 + m] = f2bf(h0);
        hlds[lrow * (AROW * 2) + nt1 * 16 + m] = f2bf(h1);
        s0 += h0; q0 += h0 * h0;
        s1 += h1; q1 += h1 * h1;
    }
    s0 += __shfl_xor(s0, 16); s0 += __shfl_xor(s0, 32);
    q0 += __shfl_xor(q0, 16); q0 += __shfl_xor(q0, 32);
    s1 += __shfl_xor(s1, 16); s1 += __shfl_xor(s1, 32);
    q1 += __shfl_xor(q1, 16); q1 += __shfl_xor(q1, 32);
    if (lane < 16) {
        float* gs = gsum + (size_t)(blockIdx.x & (NPART - 1)) * D;
        float* gq = gsq + (size_t)(blockIdx.x & (NPART - 1)) * D;
        atomicAdd(&gs[nt0 * 16 + m], s0);
        atomicAdd(&gs[nt1 * 16 + m], s1);
        atomicAdd(&gq[nt0 * 16 + m], q0);
        atomicAdd(&gq[nt1 * 16 + m], q1);
    }
    __syncthreads();

    // coalesced H store: 256 threads x one 16B chunk (16 rows x 16 chunks)
    {
        int crow = threadIdx.x >> 4;
        int cq = threadIdx.x & 15;
        uint4 v = *(const uint4*)(lA + crow * AROW + cq * 4);
        *(uint4*)(Hout + (size_t)(r0 + crow) * 64 + cq * 4) = v;
    }
}

// ---------------------------------------------------------------------------
// GEMM2 (MFMA bf16): Y = relu(scale*H+shift) @ W2 + b2, BN finalize fused
// (sums the NPART stat partials). Output tile staged in LDS, coalesced store.
__global__ __launch_bounds__(256) void gemm2_mfma_kernel(const unsigned short* __restrict__ H,
        const float* __restrict__ gsum, const float* __restrict__ gsq,
        const float* __restrict__ gamma, const float* __restrict__ beta,
        const short* __restrict__ Wp, const float* __restrict__ b,
        float* __restrict__ Yf32, unsigned* __restrict__ Yb16, int finalLayer) {
    __shared__ float s_scale[D];
    __shared__ float s_shift[D];
    __shared__ unsigned so[64 * 132];   // fp32 tile 64x132 or bf16 tile 64x68
    if (threadIdx.x < D) {
        int c = threadIdx.x;
        const float invN = 1.0f / (float)N_NODES;
        float su = 0.f, sq = 0.f;
        #pragma unroll
        for (int pp = 0; pp < NPART; pp++) {
            su += gsum[(size_t)pp * D + c];
            sq += gsq[(size_t)pp * D + c];
        }
        float mu = su * invN;
        float var = fmaxf(sq * invN - mu * mu, 0.f);
        float is = rsqrtf(var + BN_EPS);
        float sc = gamma[c] * is;
        s_scale[c] = sc;
        s_shift[c] = beta[c] - mu * sc;
    }
    __syncthreads();

    int wave = threadIdx.x >> 6, lane = threadIdx.x & 63;
    int r0 = blockIdx.x * 64;
    int m = lane & 15, g = lane >> 4;
    int arow = r0 + wave * 16 + m;
    bool valid = arow < N_NODES;

    short8 a[4];
    #pragma unroll
    for (int kt = 0; kt < 4; kt++) {
        int koff = kt * 32 + g * 8;
        if (valid) {
            short8 hv = *(const short8*)(H + (long long)arow * D + koff);
            #pragma unroll
            for (int j = 0; j < 8; j++) {
                float h = bf2f((unsigned short)hv[j]);
                float v = fmaxf(h * s_scale[koff + j] + s_shift[koff + j], 0.f);
                a[kt][j] = (short)f2bf(v);
            }
        } else {
            a[kt] = (short8)0;
        }
    }

    floatx4 acc[8];
    #pragma unroll
    for (int nt = 0; nt < 8; nt++) acc[nt] = (floatx4){0.f, 0.f, 0.f, 0.f};

    #pragma unroll
    for (int nt = 0; nt < 8; nt++) {
        #pragma unroll
        for (int kt = 0; kt < 4; kt++) {
            short8 bf = *(const short8*)(Wp + (size_t)((kt * 8 + nt) * 64 + lane) * 8);
            acc[nt] = __builtin_amdgcn_mfma_f32_16x16x32_bf16(a[kt], bf, acc[nt], 0, 0, 0);
        }
    }

    if (finalLayer) {
        float* sof = (float*)so;
        #pragma unroll
        for (int nt = 0; nt < 8; nt++) {
            int col = nt * 16 + m;
            float bcol = b[col];
            #pragma unroll
            for (int r = 0; r < 4; r++) {
                int lrow = wave * 16 + g * 4 + r;
                sof[lrow * 132 + col] = acc[nt][r] + bcol;
            }
        }
        __syncthreads();
        // 64 rows x 32 float4 chunks = 2048; 256 threads x 8
        #pragma unroll
        for (int k = 0; k < 8; k++) {
            int c = threadIdx.x + k * 256;
            int crow = c >> 5;
            int cq = c & 31;
            if (r0 + crow < N_NODES) {
                float4 v = *(const float4*)(sof + crow * 132 + cq * 4);
                *(float4*)(Yf32 + (size_t)(r0 + crow) * D + cq * 4) = v;
            }
        }
    } else {
        unsigned short* sos = (unsigned short*)so;
        #pragma unroll
        for (int nt = 0; nt < 8; nt++) {
            int col = nt * 16 + m;
            float bcol = b[col];
            #pragma unroll
            for (int r = 0; r < 4; r++) {
                int lrow = wave * 16 + g * 4 + r;
                sos[lrow * (AROW * 2) + col] = f2bf(fmaxf(acc[nt][r] + bcol, 0.f));
            }
        }
        __syncthreads();
        // 64 rows x 16 16B chunks = 1024; 256 threads x 4
        #pragma unroll
        for (int k = 0; k < 4; k++) {
            int c = threadIdx.x + k * 256;
            int crow = c >> 4;
            int cq = c & 15;
            if (r0 + crow < N_NODES) {
                uint4 v = *(const uint4*)(so + crow * AROW + cq * 4);
                *(uint4*)(Yb16 + (size_t)(r0 + crow) * 64 + cq * 4) = v;
            }
        }
    }
}

// ---------------------------------------------------------------------------
extern "C" void kernel_launch(void* const* d_in, const int* in_sizes, int n_in,
                              void* d_out, int out_size, void* d_ws, size_t ws_size,
                              hipStream_t stream) {
    const float* x      = (const float*)d_in[0];
    const void*  ei     = d_in[1];
    const float* W1     = (const float*)d_in[2];
    const float* b1     = (const float*)d_in[3];
    const float* gamma  = (const float*)d_in[4];
    const float* beta   = (const float*)d_in[5];
    const float* W2     = (const float*)d_in[6];
    const float* b2     = (const float*)d_in[7];
    const float* epsArr = (const float*)d_in[8];
    float* out = (float*)d_out;

    char* ws = (char*)d_ws;
    const size_t xbuf = (size_t)(N_NODES + 1) * D * sizeof(short);  // +1 pad row
    const size_t hbuf = (size_t)N_NODES * D * sizeof(short);
    unsigned short* Xb  = (unsigned short*)ws;                 // gather input (bf16)
    unsigned* H16       = (unsigned*)(ws + xbuf);              // gemm1 out (bf16 pairs)
    char* p             = ws + xbuf + hbuf;
    short* Wp       = (short*)p;         p += 6 * (size_t)D * D * sizeof(short);
    int* rowptr     = (int*)p;           p += (N_NODES + 1) * sizeof(int);
    int* csr        = (int*)p;           p += (size_t)NBUK * CSTRIDE * sizeof(int);
    unsigned* binned= (unsigned*)p;      p += (size_t)NBUK * BSTRIDE * sizeof(unsigned);
    int* bucketEnd  = (int*)p;           p += NBUK * sizeof(int);
    int* flag       = (int*)p;           p += sizeof(int);
    // zero region: bucketCursor[NBUK] + stats[L][2][NPART][D]
    char* zbase     = p;
    int* bucketCursor=(int*)p;           p += NBUK * sizeof(int);
    float* stats    = (float*)p;         p += (size_t)L_LAYERS * 2 * NPART * D * sizeof(float);
    int zwords      = (int)((p - zbase) / 4);

    // One-time prep: detect edge dtype, zero counters/stats/pad-row, permute
    // weights, convert x -> bf16.
    prep_kernel<<<1 + 48 + (N_NODES * D / 4) / 256, 256, 0, stream>>>(
        x, ei, flag, W1, W2, Wp, Xb, (unsigned*)zbase, zwords);

    // CSR build: 2 dispatches (merged count+bin, then per-bucket padded build).
    bin_kernel<<<NBIN_BLOCKS, 256, 0, stream>>>(ei, flag, bucketCursor, binned);
    csr_build_kernel<<<NBUK, 256, 0, stream>>>(binned, bucketCursor, rowptr, bucketEnd, csr);

    const int g1Grid = N_NODES / 16;                 // 3125, exact (50000/16)
    const int g2Grid = (N_NODES + 63) / 64;
    for (int l = 0; l < L_LAYERS; l++) {
        int fin = (l == L_LAYERS - 1) ? 1 : 0;
        float* gsum = stats + (size_t)l * 2 * NPART * D;
        float* gsq  = gsum + (size_t)NPART * D;

        gather_gemm1_kernel<<<g1Grid, 256, 0, stream>>>(
            Xb, rowptr, csr, bucketEnd, epsArr, l,
            Wp + (size_t)l * D * D, b1 + (size_t)l * D,
            H16, gsum, gsq);
        gemm2_mfma_kernel<<<g2Grid, 256, 0, stream>>>(
            (const unsigned short*)H16, gsum, gsq,
            gamma + (size_t)l * D, beta + (size_t)l * D,
            Wp + (size_t)(3 + l) * D * D, b2 + (size_t)l * D,
            out, (unsigned*)Xb, fin);
    }
}